// Round 5
// baseline (323.707 us; speedup 1.0000x reference)
//
#include <hip/hip_runtime.h>
#include <hip/hip_fp16.h>

// CapsuleLayer dynamic routing, MI355X — v3: u_hat fp16 materialized once,
// then 3 fused route+squash kernels (one block per batch element).
// 4 dispatches total: k_uhat, route<0>, route<1>, route<2>.
//
//   u_hat[b,i,c,v] = sum_d x[b,i,d] W[i,c,d,v]      (fp32 compute, fp16 store)
//   pass r: c_r = softmax_c(bias + dot_v(u_hat, osum_{r-1})), osum_0 = 0
//   s_r[b,c,v] = sum_i c_r * u_hat;  out_r = squash(s_r); osum_r = sum_j<=r out_j

#define N_I  1152
#define N_C  10
#define N_Bt 256
#define CV   160    // N_C * 16

// ---- K1: u_hat (fp16). grid (1152, bn/64), block 320 = 8 bsub x 40 (c,vq) ----
__global__ __launch_bounds__(320) void k_uhat(const float* __restrict__ inp,
                                              const float* __restrict__ W,
                                              __half* __restrict__ uhat,
                                              int b_base, int sn) {
    const int i   = blockIdx.x;
    const int bl0 = blockIdx.y * 64;
    __shared__ float Wl[N_C * 132];   // pad c-stride 128->132 (bank spread)
    {
        const int t4 = threadIdx.x * 4;                 // 0..1276
        const float4 w4 = *reinterpret_cast<const float4*>(W + (size_t)i * 1280 + t4);
        const int c = t4 >> 7, rem = t4 & 127;
        *reinterpret_cast<float4*>(&Wl[c * 132 + rem]) = w4;
    }
    __syncthreads();
    const int cv  = threadIdx.x % 40;
    const int bs0 = threadIdx.x / 40;
    const int c = cv >> 2, vq = cv & 3;
    const float* wbase = &Wl[c * 132 + vq * 4];
    float4 Wr[8];
    #pragma unroll
    for (int d = 0; d < 8; ++d) Wr[d] = *reinterpret_cast<const float4*>(wbase + d * 16);

    for (int s = 0; s < sn; ++s) {
        const int bo = bl0 + s * 8 + bs0;               // local b
        const float* ib = inp + ((size_t)(b_base + bo) * N_I + i) * 8;
        const float4 xa = *reinterpret_cast<const float4*>(ib);
        const float4 xb = *reinterpret_cast<const float4*>(ib + 4);
        const float xs[8] = {xa.x, xa.y, xa.z, xa.w, xb.x, xb.y, xb.z, xb.w};
        float4 acc = {0.f, 0.f, 0.f, 0.f};
        #pragma unroll
        for (int d = 0; d < 8; ++d) {
            acc.x += xs[d] * Wr[d].x;
            acc.y += xs[d] * Wr[d].y;
            acc.z += xs[d] * Wr[d].z;
            acc.w += xs[d] * Wr[d].w;
        }
        union { __half2 h[2]; uint2 u; } pk;
        pk.h[0] = __floats2half2_rn(acc.x, acc.y);
        pk.h[1] = __floats2half2_rn(acc.z, acc.w);
        *reinterpret_cast<uint2*>(uhat + ((size_t)bo * N_I + i) * CV + cv * 4) = pk.u;
    }
}

// ---- route+squash fused: one block per b. block 1024 = 256 ig x 4 vq ----
// MODE 0: logits = bias;               dst = squash(s)           (osum_a)
// MODE 1: logits = bias + dot(u,osum); dst = osum_in + squash(s) (osum_b)
// MODE 2: logits = bias + dot(u,osum); dst = out (global, b_off)
template <int MODE>
__global__ __launch_bounds__(1024) void k_route(const __half* __restrict__ uhat,
                                                const float* __restrict__ bias,
                                                const float* __restrict__ osum_in,
                                                float* __restrict__ dst,
                                                int b_off) {
    const int bl = blockIdx.x;
    const int t  = threadIdx.x;
    const int vq = t & 3;
    const int ig = t >> 2;                 // 0..255

    __shared__ float biasl[N_I * N_C];     // 46080 B
    __shared__ float osl[CV];              //   640 B
    __shared__ float sred[16 * CV];        // 10240 B

    for (int j = t; j < N_I * N_C / 4; j += 1024)
        reinterpret_cast<float4*>(biasl)[j] = reinterpret_cast<const float4*>(bias)[j];
    if constexpr (MODE >= 1) {
        if (t < 40)
            reinterpret_cast<float4*>(osl)[t] =
                reinterpret_cast<const float4*>(osum_in + bl * CV)[t];
    }
    __syncthreads();

    float4 sp[N_C];
    #pragma unroll
    for (int c = 0; c < N_C; ++c) sp[c] = {0.f, 0.f, 0.f, 0.f};

    const __half* ub = uhat + (size_t)bl * N_I * CV;

    #pragma unroll
    for (int k = 0; k < 5; ++k) {
        const int ii = k * 256 + ig;
        const bool ok = (ii < N_I);
        const int i = ok ? ii : 0;
        const __half* up = ub + (size_t)i * CV + vq * 4;

        float4 u[N_C];
        #pragma unroll
        for (int c = 0; c < N_C; ++c) {
            union { uint2 u2; __half2 h[2]; } r;
            r.u2 = *reinterpret_cast<const uint2*>(up + c * 16);
            const float2 f0 = __half22float2(r.h[0]);
            const float2 f1 = __half22float2(r.h[1]);
            u[c] = {f0.x, f0.y, f1.x, f1.y};
        }

        float lg[N_C];
        #pragma unroll
        for (int c = 0; c < N_C; ++c) {
            float dd = 0.f;
            if constexpr (MODE >= 1) {
                const float4 o4 = *reinterpret_cast<const float4*>(&osl[c * 16 + vq * 4]);
                dd = u[c].x * o4.x + u[c].y * o4.y + u[c].z * o4.z + u[c].w * o4.w;
                dd += __shfl_xor(dd, 1);
                dd += __shfl_xor(dd, 2);
            }
            lg[c] = dd + biasl[i * N_C + c];
        }
        float m = lg[0];
        #pragma unroll
        for (int c = 1; c < N_C; ++c) m = fmaxf(m, lg[c]);
        float ssum = 0.f;
        #pragma unroll
        for (int c = 0; c < N_C; ++c) { lg[c] = __expf(lg[c] - m); ssum += lg[c]; }
        float inv = 1.0f / ssum;
        if (!ok) inv = 0.0f;               // mask tail (ig>=128 at k=4)
        #pragma unroll
        for (int c = 0; c < N_C; ++c) {
            const float wc = lg[c] * inv;
            sp[c].x += wc * u[c].x;
            sp[c].y += wc * u[c].y;
            sp[c].z += wc * u[c].z;
            sp[c].w += wc * u[c].w;
        }
    }

    // butterfly over the 64 lanes' 16 ig-groups (bits 2..5)
    #pragma unroll
    for (int c = 0; c < N_C; ++c) {
        #pragma unroll
        for (int off = 4; off <= 32; off <<= 1) {
            sp[c].x += __shfl_xor(sp[c].x, off);
            sp[c].y += __shfl_xor(sp[c].y, off);
            sp[c].z += __shfl_xor(sp[c].z, off);
            sp[c].w += __shfl_xor(sp[c].w, off);
        }
    }
    const int lane = t & 63, wv = t >> 6;  // 16 waves
    if (lane < 4) {
        #pragma unroll
        for (int c = 0; c < N_C; ++c)
            *reinterpret_cast<float4*>(&sred[wv * CV + c * 16 + lane * 4]) = sp[c];
    }
    __syncthreads();

    if (t < CV) {                          // t = c*16 + v
        float s = 0.f;
        #pragma unroll
        for (int w = 0; w < 16; ++w) s += sred[w * CV + t];
        float sq = s * s;
        sq += __shfl_xor(sq, 1);
        sq += __shfl_xor(sq, 2);
        sq += __shfl_xor(sq, 4);
        sq += __shfl_xor(sq, 8);
        const float o = s * (sq / (1.0f + sq)) / sqrtf(sq + 1e-7f);
        if constexpr (MODE == 0)      dst[bl * CV + t] = o;
        else if constexpr (MODE == 1) dst[bl * CV + t] = osl[t] + o;
        else                          dst[((size_t)(b_off + bl)) * CV + t] = o;
    }
}

extern "C" void kernel_launch(void* const* d_in, const int* in_sizes, int n_in,
                              void* d_out, int out_size, void* d_ws, size_t ws_size,
                              hipStream_t stream) {
    (void)in_sizes; (void)n_in; (void)out_size;
    const float* inp  = (const float*)d_in[0];
    const float* W    = (const float*)d_in[1];
    const float* bias = (const float*)d_in[2];
    float* out = (float*)d_out;

    // pick largest batch segment that fits ws (ws is 256MiB in practice -> bn=256)
    int bn = 256;
    while (bn > 32) {
        size_t need = (size_t)bn * N_I * CV * 2     // uhat fp16
                    + 2ull * bn * CV * 4;           // osum_a/b
        if (need <= ws_size) break;
        bn >>= 1;
    }

    __half* uhat  = (__half*)d_ws;
    float* osum_a = (float*)((char*)d_ws + (size_t)bn * N_I * CV * 2);
    float* osum_b = osum_a + (size_t)bn * CV;

    const int sn = (bn < 64 ? bn : 64) >> 3;        // b's per block / 8
    const dim3 gu(N_I, (unsigned)((bn + 63) / 64));

    for (int b0 = 0; b0 < N_Bt; b0 += bn) {
        k_uhat<<<gu, 320, 0, stream>>>(inp, W, uhat, b0, sn);
        k_route<0><<<bn, 1024, 0, stream>>>(uhat, bias, nullptr, osum_a, 0);
        k_route<1><<<bn, 1024, 0, stream>>>(uhat, bias, osum_a, osum_b, 0);
        k_route<2><<<bn, 1024, 0, stream>>>(uhat, bias, osum_b, out, b0);
    }
}

// Round 7
// 207.552 us; speedup vs baseline: 1.5596x; 1.5596x over previous
//
#include <hip/hip_runtime.h>
#include <hip/hip_fp16.h>

// CapsuleLayer dynamic routing, MI355X — v4: u_hat fp16 once (94.4MB), then
// 3 wide-parallel routing passes (2304 blocks) with squash folded into the
// NEXT pass's prologue (recomputed per block from tiny s_part buffers).
// 5 dispatches: k_uhat, route<0>, route<1>, route<2>, k_final.
//
//   u_hat[b,i,c,v] = sum_d x[b,i,d] W[i,c,d,v]      (fp32 compute, fp16 store)
//   pass r: c_r = softmax_c(bias + dot_v(u_hat, osum_{r-1})), osum_0 = 0
//   s_r[b,c,v] = sum_i c_r * u_hat;  out_r = squash(s_r); osum_r = sum_j<=r out_j

#define N_I  1152
#define N_C  10
#define N_Bt 256
#define CV   160    // N_C * 16
#define NSPL 9      // i-splits per routing pass
#define IPB  128    // i per route block (= 512 threads / 4 vq)

// ---- K1: u_hat (fp16). grid (1152, bn/64), block 320 = 8 bsub x 40 (c,vq) ----
__global__ __launch_bounds__(320) void k_uhat(const float* __restrict__ inp,
                                              const float* __restrict__ W,
                                              __half* __restrict__ uhat,
                                              int b_base, int sn) {
    const int i   = blockIdx.x;
    const int bl0 = blockIdx.y * 64;
    __shared__ float Wl[N_C * 132];   // pad c-stride 128->132 (bank spread)
    {
        const int t4 = threadIdx.x * 4;                 // 0..1276
        const float4 w4 = *reinterpret_cast<const float4*>(W + (size_t)i * 1280 + t4);
        const int c = t4 >> 7, rem = t4 & 127;
        *reinterpret_cast<float4*>(&Wl[c * 132 + rem]) = w4;
    }
    __syncthreads();
    const int cv  = threadIdx.x % 40;
    const int bs0 = threadIdx.x / 40;
    const int c = cv >> 2, vq = cv & 3;
    const float* wbase = &Wl[c * 132 + vq * 4];
    float4 Wr[8];
    #pragma unroll
    for (int d = 0; d < 8; ++d) Wr[d] = *reinterpret_cast<const float4*>(wbase + d * 16);

    for (int s = 0; s < sn; ++s) {
        const int bo = bl0 + s * 8 + bs0;               // local b
        const float* ib = inp + ((size_t)(b_base + bo) * N_I + i) * 8;
        const float4 xa = *reinterpret_cast<const float4*>(ib);
        const float4 xb = *reinterpret_cast<const float4*>(ib + 4);
        const float xs[8] = {xa.x, xa.y, xa.z, xa.w, xb.x, xb.y, xb.z, xb.w};
        float4 acc = {0.f, 0.f, 0.f, 0.f};
        #pragma unroll
        for (int d = 0; d < 8; ++d) {
            acc.x += xs[d] * Wr[d].x;
            acc.y += xs[d] * Wr[d].y;
            acc.z += xs[d] * Wr[d].z;
            acc.w += xs[d] * Wr[d].w;
        }
        union { __half2 h[2]; uint2 u; } pk;
        pk.h[0] = __floats2half2_rn(acc.x, acc.y);
        pk.h[1] = __floats2half2_rn(acc.z, acc.w);
        *reinterpret_cast<uint2*>(uhat + ((size_t)bo * N_I + i) * CV + cv * 4) = pk.u;
    }
}

__device__ __forceinline__ float squash16(float s) {
    // norm^2 over the 16-thread v-group (16-aligned within a wave)
    float sq = s * s;
    sq += __shfl_xor(sq, 1);
    sq += __shfl_xor(sq, 2);
    sq += __shfl_xor(sq, 4);
    sq += __shfl_xor(sq, 8);
    return s * (sq / (1.0f + sq)) * rsqrtf(sq + 1e-7f);
}

// ---- route pass. grid = bn*NSPL blocks, 512 thr = 128 ig x 4 vq; 1 i/thread ----
// MODE 0: logits = bias                       (pass 1)
// MODE 1: osum = squash(sum s_a)              (pass 2)
// MODE 2: osum = squash(sum s_a)+squash(sum s_b)  (pass 3)
template <int MODE>
__global__ __launch_bounds__(512) void k_route(const __half* __restrict__ uhat,
                                               const float* __restrict__ bias,
                                               const float* __restrict__ s_a,
                                               const float* __restrict__ s_b,
                                               float* __restrict__ s_out) {
    const int bl  = blockIdx.x / NSPL;
    const int spl = blockIdx.x % NSPL;
    const int t   = threadIdx.x;
    const int vq  = t & 3;
    const int ig  = t >> 2;               // 0..127

    __shared__ float osl[CV];
    __shared__ float sred[8 * CV];        // 8 waves x 160

    // ---- prologue: recompute osum from s_part partials (tiny, L2-hot) ----
    if constexpr (MODE >= 1) {
        if (t < CV) {
            float s1 = 0.f;
            #pragma unroll
            for (int k = 0; k < NSPL; ++k) s1 += s_a[((size_t)bl * NSPL + k) * CV + t];
            float os = squash16(s1);
            if constexpr (MODE == 2) {
                float s2 = 0.f;
                #pragma unroll
                for (int k = 0; k < NSPL; ++k) s2 += s_b[((size_t)bl * NSPL + k) * CV + t];
                os += squash16(s2);
            }
            osl[t] = os;
        }
        __syncthreads();
    }

    // ---- main: one i per thread ----
    const int i = spl * IPB + ig;
    const __half* up = uhat + ((size_t)bl * N_I + i) * CV + vq * 4;

    float4 u[N_C];
    #pragma unroll
    for (int c = 0; c < N_C; ++c) {
        union { uint2 u2; __half2 h[2]; } r;
        r.u2 = *reinterpret_cast<const uint2*>(up + c * 16);
        const float2 f0 = __half22float2(r.h[0]);
        const float2 f1 = __half22float2(r.h[1]);
        u[c] = {f0.x, f0.y, f1.x, f1.y};
    }

    float lg[N_C];
    #pragma unroll
    for (int c = 0; c < N_C; ++c) {
        float dd = 0.f;
        if constexpr (MODE >= 1) {
            const float4 o4 = *reinterpret_cast<const float4*>(&osl[c * 16 + vq * 4]);
            dd = u[c].x * o4.x + u[c].y * o4.y + u[c].z * o4.z + u[c].w * o4.w;
            dd += __shfl_xor(dd, 1);
            dd += __shfl_xor(dd, 2);
        }
        lg[c] = dd + bias[i * N_C + c];
    }
    float m = lg[0];
    #pragma unroll
    for (int c = 1; c < N_C; ++c) m = fmaxf(m, lg[c]);
    float ssum = 0.f;
    #pragma unroll
    for (int c = 0; c < N_C; ++c) { lg[c] = __expf(lg[c] - m); ssum += lg[c]; }
    const float inv = 1.0f / ssum;

    float4 sp[N_C];
    #pragma unroll
    for (int c = 0; c < N_C; ++c) {
        const float wc = lg[c] * inv;
        sp[c] = {wc * u[c].x, wc * u[c].y, wc * u[c].z, wc * u[c].w};
    }

    // butterfly over the 16 ig-groups within each wave (lane bits 2..5)
    #pragma unroll
    for (int c = 0; c < N_C; ++c) {
        #pragma unroll
        for (int off = 4; off <= 32; off <<= 1) {
            sp[c].x += __shfl_xor(sp[c].x, off);
            sp[c].y += __shfl_xor(sp[c].y, off);
            sp[c].z += __shfl_xor(sp[c].z, off);
            sp[c].w += __shfl_xor(sp[c].w, off);
        }
    }
    const int lane = t & 63, wv = t >> 6;  // 8 waves
    if (lane < 4) {
        #pragma unroll
        for (int c = 0; c < N_C; ++c)
            *reinterpret_cast<float4*>(&sred[wv * CV + c * 16 + lane * 4]) = sp[c];
    }
    __syncthreads();

    if (t < CV) {                          // t = c*16 + v
        float s = 0.f;
        #pragma unroll
        for (int w = 0; w < 8; ++w) s += sred[w * CV + t];
        s_out[((size_t)bl * NSPL + spl) * CV + t] = s;
    }
}

// ---- final: sum partials of pass 3, squash, write out ----
__global__ __launch_bounds__(CV) void k_final(const float* __restrict__ s_c,
                                              float* __restrict__ out, int b_off) {
    const int bl = blockIdx.x;
    const int t  = threadIdx.x;            // c*16+v
    float s = 0.f;
    #pragma unroll
    for (int k = 0; k < NSPL; ++k) s += s_c[((size_t)bl * NSPL + k) * CV + t];
    out[((size_t)(b_off + bl)) * CV + t] = squash16(s);
}

extern "C" void kernel_launch(void* const* d_in, const int* in_sizes, int n_in,
                              void* d_out, int out_size, void* d_ws, size_t ws_size,
                              hipStream_t stream) {
    (void)in_sizes; (void)n_in; (void)out_size;
    const float* inp  = (const float*)d_in[0];
    const float* W    = (const float*)d_in[1];
    const float* bias = (const float*)d_in[2];
    float* out = (float*)d_out;

    // pick largest batch segment that fits ws (ws is 256MiB in practice -> bn=256)
    int bn = 256;
    while (bn > 32) {
        size_t need = (size_t)bn * N_I * CV * 2       // uhat fp16
                    + 3ull * bn * NSPL * CV * 4;      // s_a, s_b, s_c
        if (need <= ws_size) break;
        bn >>= 1;
    }

    __half* uhat = (__half*)d_ws;
    float* s_a = (float*)((char*)d_ws + (size_t)bn * N_I * CV * 2);
    float* s_b = s_a + (size_t)bn * NSPL * CV;
    float* s_c = s_b + (size_t)bn * NSPL * CV;

    const int sn = (bn < 64 ? bn : 64) >> 3;          // b's per block / 8
    const dim3 gu(N_I, (unsigned)((bn + 63) / 64));

    for (int b0 = 0; b0 < N_Bt; b0 += bn) {
        k_uhat<<<gu, 320, 0, stream>>>(inp, W, uhat, b0, sn);
        k_route<0><<<bn * NSPL, 512, 0, stream>>>(uhat, bias, nullptr, nullptr, s_a);
        k_route<1><<<bn * NSPL, 512, 0, stream>>>(uhat, bias, s_a, nullptr, s_b);
        k_route<2><<<bn * NSPL, 512, 0, stream>>>(uhat, bias, s_a, s_b, s_c);
        k_final<<<bn, CV, 0, stream>>>(s_c, out, b0);
    }
}

// Round 12
// 165.970 us; speedup vs baseline: 1.9504x; 1.2505x over previous
//
#include <hip/hip_runtime.h>
#include <hip/hip_fp16.h>

// CapsuleLayer dynamic routing, MI355X — v5.
//  k_uhat: fp16 u_hat once (94.4MB), 2 b/lane via float2 ext-vector (v_pk_fma_f32)
//  k_route: 3 wide passes, Ki=3 i per thread (butterfly epilogue amortized 3x)
//  squash folded into next pass's prologue from tiny s_part buffers.
// 5 dispatches: k_uhat, route<0>, route<1>, route<2>, k_final.

#define N_I  1152
#define N_C  10
#define N_Bt 256
#define CV   160    // N_C * 16
#define NSPL 6      // i-splits per routing pass
#define KI   3      // i per thread (serial)
#define IPB  192    // i per route block = 64 ig * KI

typedef float v2f __attribute__((ext_vector_type(2)));

// ---- K1: u_hat (fp16). grid (1152, bn/64), block 320 = 8 pair-slots x 40 (c,vq)
// Each lane computes TWO b's packed in float2 -> v_pk_fma_f32.
__global__ __launch_bounds__(320) void k_uhat(const float* __restrict__ inp,
                                              const float* __restrict__ W,
                                              __half* __restrict__ uhat,
                                              int b_base, int sn) {
    const int i   = blockIdx.x;
    const int bl0 = blockIdx.y * 64;
    __shared__ float Wl[N_C * 132];   // pad c-stride 128->132 (bank spread)
    {
        const int t4 = threadIdx.x * 4;                 // 0..1276
        const float4 w4 = *reinterpret_cast<const float4*>(W + (size_t)i * 1280 + t4);
        const int c = t4 >> 7, rem = t4 & 127;
        *reinterpret_cast<float4*>(&Wl[c * 132 + rem]) = w4;
    }
    __syncthreads();
    const int cv  = threadIdx.x % 40;
    const int bs0 = threadIdx.x / 40;   // 0..7 (pair slot)
    const int c = cv >> 2, vq = cv & 3;
    const float* wbase = &Wl[c * 132 + vq * 4];
    float4 Wr[8];
    #pragma unroll
    for (int d = 0; d < 8; ++d) Wr[d] = *reinterpret_cast<const float4*>(wbase + d * 16);

    for (int s = 0; s < sn; ++s) {
        const int bo = bl0 + s * 16 + bs0 * 2;          // local b (even)
        const float* ib0 = inp + ((size_t)(b_base + bo) * N_I + i) * 8;
        const float* ib1 = ib0 + (size_t)N_I * 8;
        const float4 a0 = *reinterpret_cast<const float4*>(ib0);
        const float4 a1 = *reinterpret_cast<const float4*>(ib0 + 4);
        const float4 b0 = *reinterpret_cast<const float4*>(ib1);
        const float4 b1 = *reinterpret_cast<const float4*>(ib1 + 4);
        v2f xp[8] = {{a0.x, b0.x}, {a0.y, b0.y}, {a0.z, b0.z}, {a0.w, b0.w},
                     {a1.x, b1.x}, {a1.y, b1.y}, {a1.z, b1.z}, {a1.w, b1.w}};
        v2f ac0 = {0.f, 0.f}, ac1 = {0.f, 0.f}, ac2 = {0.f, 0.f}, ac3 = {0.f, 0.f};
        #pragma unroll
        for (int d = 0; d < 8; ++d) {
            ac0 += xp[d] * Wr[d].x;
            ac1 += xp[d] * Wr[d].y;
            ac2 += xp[d] * Wr[d].z;
            ac3 += xp[d] * Wr[d].w;
        }
        union { __half2 h[2]; uint2 u; } p0, p1;
        p0.h[0] = __floats2half2_rn(ac0.x, ac1.x);
        p0.h[1] = __floats2half2_rn(ac2.x, ac3.x);
        p1.h[0] = __floats2half2_rn(ac0.y, ac1.y);
        p1.h[1] = __floats2half2_rn(ac2.y, ac3.y);
        __half* ub = uhat + ((size_t)bo * N_I + i) * CV + cv * 4;
        *reinterpret_cast<uint2*>(ub) = p0.u;
        *reinterpret_cast<uint2*>(ub + (size_t)N_I * CV) = p1.u;
    }
}

__device__ __forceinline__ float squash16(float s) {
    // norm^2 over the 16-thread v-group (16-aligned within a wave)
    float sq = s * s;
    sq += __shfl_xor(sq, 1);
    sq += __shfl_xor(sq, 2);
    sq += __shfl_xor(sq, 4);
    sq += __shfl_xor(sq, 8);
    return s * (sq / (1.0f + sq)) * rsqrtf(sq + 1e-7f);
}

// ---- route pass. grid = bn*NSPL, block 256 = 64 ig x 4 vq; KI=3 i per thread ----
// MODE 0: logits = bias                           (pass 1)
// MODE 1: osum = squash(sum s_a)                  (pass 2)
// MODE 2: osum = squash(sum s_a)+squash(sum s_b)  (pass 3)
template <int MODE>
__global__ __launch_bounds__(256) void k_route(const __half* __restrict__ uhat,
                                               const float* __restrict__ bias,
                                               const float* __restrict__ s_a,
                                               const float* __restrict__ s_b,
                                               float* __restrict__ s_out) {
    const int bl  = blockIdx.x / NSPL;
    const int spl = blockIdx.x % NSPL;
    const int t   = threadIdx.x;
    const int vq  = t & 3;
    const int ig  = t >> 2;               // 0..63

    __shared__ float osl[CV];
    __shared__ float sred[4 * CV];        // 4 waves x 160

    // ---- prologue: recompute osum from s_part partials (tiny, L2-hot) ----
    if constexpr (MODE >= 1) {
        if (t < CV) {
            float s1 = 0.f;
            #pragma unroll
            for (int k = 0; k < NSPL; ++k) s1 += s_a[((size_t)bl * NSPL + k) * CV + t];
            float os = squash16(s1);
            if constexpr (MODE == 2) {
                float s2 = 0.f;
                #pragma unroll
                for (int k = 0; k < NSPL; ++k) s2 += s_b[((size_t)bl * NSPL + k) * CV + t];
                os += squash16(s2);
            }
            osl[t] = os;
        }
        __syncthreads();
    }

    float4 sp[N_C];
    #pragma unroll
    for (int c = 0; c < N_C; ++c) sp[c] = {0.f, 0.f, 0.f, 0.f};

    #pragma unroll
    for (int kk = 0; kk < KI; ++kk) {
        const int i = spl * IPB + kk * 64 + ig;
        const __half* up = uhat + ((size_t)bl * N_I + i) * CV + vq * 4;

        float4 u[N_C];
        #pragma unroll
        for (int c = 0; c < N_C; ++c) {
            union { uint2 u2; __half2 h[2]; } r;
            r.u2 = *reinterpret_cast<const uint2*>(up + c * 16);
            const float2 f0 = __half22float2(r.h[0]);
            const float2 f1 = __half22float2(r.h[1]);
            u[c] = {f0.x, f0.y, f1.x, f1.y};
        }

        float lg[N_C];
        #pragma unroll
        for (int c = 0; c < N_C; ++c) {
            float dd = 0.f;
            if constexpr (MODE >= 1) {
                const float4 o4 = *reinterpret_cast<const float4*>(&osl[c * 16 + vq * 4]);
                dd = u[c].x * o4.x + u[c].y * o4.y + u[c].z * o4.z + u[c].w * o4.w;
                dd += __shfl_xor(dd, 1);   // quad-perm DPP class
                dd += __shfl_xor(dd, 2);
            }
            lg[c] = dd + bias[i * N_C + c];
        }
        float m = lg[0];
        #pragma unroll
        for (int c = 1; c < N_C; ++c) m = fmaxf(m, lg[c]);
        float ssum = 0.f;
        #pragma unroll
        for (int c = 0; c < N_C; ++c) { lg[c] = __expf(lg[c] - m); ssum += lg[c]; }
        const float inv = 1.0f / ssum;
        #pragma unroll
        for (int c = 0; c < N_C; ++c) {
            const float wc = lg[c] * inv;
            sp[c].x += wc * u[c].x;
            sp[c].y += wc * u[c].y;
            sp[c].z += wc * u[c].z;
            sp[c].w += wc * u[c].w;
        }
    }

    // butterfly over the 16 ig-groups within each wave (lane bits 2..5)
    #pragma unroll
    for (int c = 0; c < N_C; ++c) {
        #pragma unroll
        for (int off = 4; off <= 32; off <<= 1) {
            sp[c].x += __shfl_xor(sp[c].x, off);
            sp[c].y += __shfl_xor(sp[c].y, off);
            sp[c].z += __shfl_xor(sp[c].z, off);
            sp[c].w += __shfl_xor(sp[c].w, off);
        }
    }
    const int lane = t & 63, wv = t >> 6;  // 4 waves
    if (lane < 4) {
        #pragma unroll
        for (int c = 0; c < N_C; ++c)
            *reinterpret_cast<float4*>(&sred[wv * CV + c * 16 + lane * 4]) = sp[c];
    }
    __syncthreads();

    if (t < CV) {                          // t = c*16 + v
        const float s = sred[t] + sred[CV + t] + sred[2 * CV + t] + sred[3 * CV + t];
        s_out[((size_t)bl * NSPL + spl) * CV + t] = s;
    }
}

// ---- final: sum partials of pass 3, squash, write out ----
__global__ __launch_bounds__(CV) void k_final(const float* __restrict__ s_c,
                                              float* __restrict__ out, int b_off) {
    const int bl = blockIdx.x;
    const int t  = threadIdx.x;            // c*16+v
    float s = 0.f;
    #pragma unroll
    for (int k = 0; k < NSPL; ++k) s += s_c[((size_t)bl * NSPL + k) * CV + t];
    out[((size_t)(b_off + bl)) * CV + t] = squash16(s);
}

extern "C" void kernel_launch(void* const* d_in, const int* in_sizes, int n_in,
                              void* d_out, int out_size, void* d_ws, size_t ws_size,
                              hipStream_t stream) {
    (void)in_sizes; (void)n_in; (void)out_size;
    const float* inp  = (const float*)d_in[0];
    const float* W    = (const float*)d_in[1];
    const float* bias = (const float*)d_in[2];
    float* out = (float*)d_out;

    // pick largest batch segment that fits ws (ws is 256MiB in practice -> bn=256)
    int bn = 256;
    while (bn > 32) {
        size_t need = (size_t)bn * N_I * CV * 2       // uhat fp16
                    + 3ull * bn * NSPL * CV * 4;      // s_a, s_b, s_c
        if (need <= ws_size) break;
        bn >>= 1;
    }

    __half* uhat = (__half*)d_ws;
    float* s_a = (float*)((char*)d_ws + (size_t)bn * N_I * CV * 2);
    float* s_b = s_a + (size_t)bn * NSPL * CV;
    float* s_c = s_b + (size_t)bn * NSPL * CV;

    const int sn = (bn < 64 ? bn : 64) / 16;          // pair-iterations per block
    const dim3 gu(N_I, (unsigned)((bn + 63) / 64));

    for (int b0 = 0; b0 < N_Bt; b0 += bn) {
        k_uhat<<<gu, 320, 0, stream>>>(inp, W, uhat, b0, sn);
        k_route<0><<<bn * NSPL, 256, 0, stream>>>(uhat, bias, nullptr, nullptr, s_a);
        k_route<1><<<bn * NSPL, 256, 0, stream>>>(uhat, bias, s_a, nullptr, s_b);
        k_route<2><<<bn * NSPL, 256, 0, stream>>>(uhat, bias, s_a, s_b, s_c);
        k_final<<<bn, CV, 0, stream>>>(s_c, out, b0);
    }
}